// Round 6
// baseline (475.177 us; speedup 1.0000x reference)
//
#include <hip/hip_runtime.h>
#include <math.h>

#define FF 256
#define HH 64

typedef __attribute__((ext_vector_type(8))) short short8;
typedef __attribute__((ext_vector_type(8))) unsigned short ushort8;
typedef __attribute__((ext_vector_type(4))) float f32x4;

__device__ __forceinline__ float gelu_f(float x) {
    return 0.5f * x * (1.0f + erff(x * 0.70710678118654752f));
}

__device__ __forceinline__ unsigned short bf16rne(float f) {
    unsigned u = __float_as_uint(f);
    unsigned r = u + 0x7FFFu + ((u >> 16) & 1u);
    return (unsigned short)(r >> 16);
}
__device__ __forceinline__ float bf16tof(unsigned short s) {
    return __uint_as_float(((unsigned)s) << 16);
}

// split f into bf16 hi + bf16 lo (RNE)
__device__ __forceinline__ void bf16split(float f, short& hi, short& lo) {
    unsigned u = __float_as_uint(f);
    unsigned r = u + 0x7FFFu + ((u >> 16) & 1u);
    hi = (short)(r >> 16);
    float fh = __uint_as_float(r & 0xFFFF0000u);
    float fl = f - fh;
    unsigned u2 = __float_as_uint(fl);
    unsigned r2 = u2 + 0x7FFFu + ((u2 >> 16) & 1u);
    lo = (short)(r2 >> 16);
}

// ---- W fragment tables in workspace (bf16 hi/lo, fragment-ordered) ----
__global__ __launch_bounds__(256) void k_wprep(
        const float* __restrict__ Wp,
        const float* __restrict__ Wq1, const float* __restrict__ Wk1, const float* __restrict__ Wv1,
        const float* __restrict__ Wq2, const float* __restrict__ Wk2, const float* __restrict__ Wv2,
        short* __restrict__ wf) {
    int total = 16384 + 6 * 4096;
    for (int gid = blockIdx.x * 256 + threadIdx.x; gid < total; gid += gridDim.x * 256) {
        const float* W;
        int fid, hibase, lobase;
        if (gid < 16384) {
            W = Wp; fid = gid; hibase = 0; lobase = 16384;
        } else {
            int t = gid - 16384;
            int m = t >> 12;
            fid = t & 4095;
            switch (m) {
                case 0: W = Wq1; break;
                case 1: W = Wk1; break;
                case 2: W = Wv1; break;
                case 3: W = Wq2; break;
                case 4: W = Wk2; break;
                default: W = Wv2; break;
            }
            hibase = 32768 + m * 8192;
            lobase = hibase + 4096;
        }
        int j    = fid & 7;
        int lane = (fid >> 3) & 63;
        int ct   = (fid >> 9) & 3;
        int s    = fid >> 11;
        int k    = s * 32 + (lane >> 4) * 8 + j;
        int col  = ct * 16 + (lane & 15);
        short hi, lo;
        bf16split(W[k * HH + col], hi, lo);
        wf[hibase + fid] = hi;
        wf[lobase + fid] = lo;
    }
}

// ---------------- CSR build ----------------
__global__ __launch_bounds__(256) void k_degree(const int* __restrict__ dst,
        int* __restrict__ deg, int E) {
    int e0 = (blockIdx.x * 256 + threadIdx.x) * 4;
    if (e0 + 3 < E) {
        int4 d4 = *reinterpret_cast<const int4*>(dst + e0);
        atomicAdd(&deg[d4.x], 1);
        atomicAdd(&deg[d4.y], 1);
        atomicAdd(&deg[d4.z], 1);
        atomicAdd(&deg[d4.w], 1);
    } else {
        for (int e = e0; e < E; ++e) atomicAdd(&deg[dst[e]], 1);
    }
}

__global__ __launch_bounds__(256) void k_scan1(const int* __restrict__ deg,
        int* __restrict__ out, int* __restrict__ bsums, int n) {
    __shared__ int lds[256];
    int t = threadIdx.x;
    int base = blockIdx.x * 1024 + t * 4;
    int v0 = (base     < n) ? deg[base]     : 0;
    int v1 = (base + 1 < n) ? deg[base + 1] : 0;
    int v2 = (base + 2 < n) ? deg[base + 2] : 0;
    int v3 = (base + 3 < n) ? deg[base + 3] : 0;
    int s = v0 + v1 + v2 + v3;
    int val = s;
    lds[t] = val;
    __syncthreads();
    #pragma unroll
    for (int off = 1; off < 256; off <<= 1) {
        int tmp = (t >= off) ? lds[t - off] : 0;
        __syncthreads();
        val += tmp;
        lds[t] = val;
        __syncthreads();
    }
    if (t == 255) bsums[blockIdx.x] = val;
    int excl = val - s;
    if (base     < n) out[base]     = excl;
    if (base + 1 < n) out[base + 1] = excl + v0;
    if (base + 2 < n) out[base + 2] = excl + v0 + v1;
    if (base + 3 < n) out[base + 3] = excl + v0 + v1 + v2;
}

__global__ __launch_bounds__(256) void k_scan2(const int* __restrict__ bsums,
        int* __restrict__ boffs, int nb) {
    __shared__ int lds[256];
    int t = threadIdx.x;
    int s = (t < nb) ? bsums[t] : 0;
    int val = s;
    lds[t] = val;
    __syncthreads();
    #pragma unroll
    for (int off = 1; off < 256; off <<= 1) {
        int tmp = (t >= off) ? lds[t - off] : 0;
        __syncthreads();
        val += tmp;
        lds[t] = val;
        __syncthreads();
    }
    if (t < nb) boffs[t] = val - s;
}

// finalize rowptr AND initialize cursor = rowptr
__global__ __launch_bounds__(256) void k_scan3(int* __restrict__ rowptr,
        int* __restrict__ cursor, const int* __restrict__ boffs, int n, int E) {
    int i = blockIdx.x * 256 + threadIdx.x;
    if (i < n) {
        int v = rowptr[i] + boffs[i >> 10];
        rowptr[i] = v;
        cursor[i] = v;
    }
    if (i == n) rowptr[n] = E;
}

// fill: esrc (random scatter, 1 store) + inv (coalesced)
__global__ __launch_bounds__(256) void k_fill(const int* __restrict__ src,
        const int* __restrict__ dst, int* __restrict__ cursor,
        int* __restrict__ esrc, int* __restrict__ inv, int E) {
    int e0 = (blockIdx.x * 256 + threadIdx.x) * 4;
    if (e0 + 3 < E) {
        int4 d4 = *reinterpret_cast<const int4*>(dst + e0);
        int4 s4 = *reinterpret_cast<const int4*>(src + e0);
        int p0 = atomicAdd(&cursor[d4.x], 1);
        int p1 = atomicAdd(&cursor[d4.y], 1);
        int p2 = atomicAdd(&cursor[d4.z], 1);
        int p3 = atomicAdd(&cursor[d4.w], 1);
        esrc[p0] = s4.x;
        esrc[p1] = s4.y;
        esrc[p2] = s4.z;
        esrc[p3] = s4.w;
        *reinterpret_cast<int4*>(inv + e0) = (int4){p0, p1, p2, p3};
    } else {
        for (int e = e0; e < E; ++e) {
            int pos = atomicAdd(&cursor[dst[e]], 1);
            esrc[pos] = src[e];
            inv[e] = pos;
        }
    }
}

// edge-order attention coefficients: coalesced write, gathered read
__global__ __launch_bounds__(256) void k_attn(const float* __restrict__ ecsr,
        const int* __restrict__ inv, float* __restrict__ attn, int E) {
    int e0 = (blockIdx.x * 256 + threadIdx.x) * 4;
    if (e0 + 3 < E) {
        int4 i4 = *reinterpret_cast<const int4*>(inv + e0);
        float4 a;
        a.x = ecsr[i4.x]; a.y = ecsr[i4.y]; a.z = ecsr[i4.z]; a.w = ecsr[i4.w];
        *reinterpret_cast<float4*>(attn + e0) = a;
    } else {
        for (int e = e0; e < E; ++e) attn[e] = ecsr[inv[e]];
    }
}

// ---------------- proj GEMM + gelu via MFMA (split-bf16, 3 terms) ----------------
__global__ __launch_bounds__(256) void k_proj(const float* __restrict__ x,
        const short* __restrict__ wf, const float* __restrict__ b,
        float* __restrict__ h, int n) {
    int lane = threadIdx.x & 63;
    int w    = threadIdx.x >> 6;
    int m    = lane & 15, g = lane >> 4;
    int rowc = min(blockIdx.x * 64 + w * 16 + m, n - 1);
    const float* xrow = x + (size_t)rowc * FF + g * 8;
    const short* wlo = wf + 16384;
    f32x4 acc[4];
    #pragma unroll
    for (int ct = 0; ct < 4; ++ct) acc[ct] = (f32x4){0.f, 0.f, 0.f, 0.f};
    #pragma unroll
    for (int s = 0; s < 8; ++s) {
        float4 a0 = *reinterpret_cast<const float4*>(xrow + s * 32);
        float4 a1 = *reinterpret_cast<const float4*>(xrow + s * 32 + 4);
        float av[8] = {a0.x, a0.y, a0.z, a0.w, a1.x, a1.y, a1.z, a1.w};
        short8 ah, al;
        #pragma unroll
        for (int j = 0; j < 8; ++j) { short hi, lo; bf16split(av[j], hi, lo); ah[j] = hi; al[j] = lo; }
        #pragma unroll
        for (int ct = 0; ct < 4; ++ct) {
            int fo = ((s * 4 + ct) * 64 + lane) * 8;
            short8 bh = *reinterpret_cast<const short8*>(wf + fo);
            short8 bl = *reinterpret_cast<const short8*>(wlo + fo);
            acc[ct] = __builtin_amdgcn_mfma_f32_16x16x32_bf16(ah, bh, acc[ct], 0, 0, 0);
            acc[ct] = __builtin_amdgcn_mfma_f32_16x16x32_bf16(al, bh, acc[ct], 0, 0, 0);
            acc[ct] = __builtin_amdgcn_mfma_f32_16x16x32_bf16(ah, bl, acc[ct], 0, 0, 0);
        }
    }
    int orow0 = blockIdx.x * 64 + w * 16 + g * 4;
    #pragma unroll
    for (int ct = 0; ct < 4; ++ct) {
        int col = ct * 16 + m;
        float bias = b[col];
        #pragma unroll
        for (int r = 0; r < 4; ++r) {
            int row = orow0 + r;
            if (row < n) h[(size_t)row * HH + col] = gelu_f(acc[ct][r] + bias);
        }
    }
}

// ---------------- fused QKV GEMM via MFMA; k,v written as bf16 ----------------
__global__ __launch_bounds__(256) void k_qkv(const float* __restrict__ hsrc,
        const short* __restrict__ wfq, const short* __restrict__ wfk, const short* __restrict__ wfv,
        float* __restrict__ q, unsigned short* __restrict__ kb, unsigned short* __restrict__ vb, int n) {
    int lane = threadIdx.x & 63;
    int w    = threadIdx.x >> 6;
    int m    = lane & 15, g = lane >> 4;
    int rowc = min(blockIdx.x * 64 + w * 16 + m, n - 1);
    const float* hrow = hsrc + (size_t)rowc * HH + g * 8;
    f32x4 aq[4], ak[4], av_[4];
    #pragma unroll
    for (int ct = 0; ct < 4; ++ct) {
        aq[ct] = (f32x4){0.f, 0.f, 0.f, 0.f};
        ak[ct] = (f32x4){0.f, 0.f, 0.f, 0.f};
        av_[ct] = (f32x4){0.f, 0.f, 0.f, 0.f};
    }
    #pragma unroll
    for (int s = 0; s < 2; ++s) {
        float4 a0 = *reinterpret_cast<const float4*>(hrow + s * 32);
        float4 a1 = *reinterpret_cast<const float4*>(hrow + s * 32 + 4);
        float avv[8] = {a0.x, a0.y, a0.z, a0.w, a1.x, a1.y, a1.z, a1.w};
        short8 ah, al;
        #pragma unroll
        for (int j = 0; j < 8; ++j) { short hi, lo; bf16split(avv[j], hi, lo); ah[j] = hi; al[j] = lo; }
        #pragma unroll
        for (int ct = 0; ct < 4; ++ct) {
            int fo = ((s * 4 + ct) * 64 + lane) * 8;
            short8 qh = *reinterpret_cast<const short8*>(wfq + fo);
            short8 ql = *reinterpret_cast<const short8*>(wfq + 4096 + fo);
            short8 kh = *reinterpret_cast<const short8*>(wfk + fo);
            short8 kl = *reinterpret_cast<const short8*>(wfk + 4096 + fo);
            short8 vh = *reinterpret_cast<const short8*>(wfv + fo);
            short8 vl = *reinterpret_cast<const short8*>(wfv + 4096 + fo);
            aq[ct] = __builtin_amdgcn_mfma_f32_16x16x32_bf16(ah, qh, aq[ct], 0, 0, 0);
            aq[ct] = __builtin_amdgcn_mfma_f32_16x16x32_bf16(al, qh, aq[ct], 0, 0, 0);
            aq[ct] = __builtin_amdgcn_mfma_f32_16x16x32_bf16(ah, ql, aq[ct], 0, 0, 0);
            ak[ct] = __builtin_amdgcn_mfma_f32_16x16x32_bf16(ah, kh, ak[ct], 0, 0, 0);
            ak[ct] = __builtin_amdgcn_mfma_f32_16x16x32_bf16(al, kh, ak[ct], 0, 0, 0);
            ak[ct] = __builtin_amdgcn_mfma_f32_16x16x32_bf16(ah, kl, ak[ct], 0, 0, 0);
            av_[ct] = __builtin_amdgcn_mfma_f32_16x16x32_bf16(ah, vh, av_[ct], 0, 0, 0);
            av_[ct] = __builtin_amdgcn_mfma_f32_16x16x32_bf16(al, vh, av_[ct], 0, 0, 0);
            av_[ct] = __builtin_amdgcn_mfma_f32_16x16x32_bf16(ah, vl, av_[ct], 0, 0, 0);
        }
    }
    int orow0 = blockIdx.x * 64 + w * 16 + g * 4;
    #pragma unroll
    for (int ct = 0; ct < 4; ++ct) {
        int col = ct * 16 + m;
        #pragma unroll
        for (int r = 0; r < 4; ++r) {
            int row = orow0 + r;
            if (row < n) {
                q[(size_t)row * HH + col]  = aq[ct][r];
                kb[(size_t)row * HH + col] = bf16rne(ak[ct][r]);
                vb[(size_t)row * HH + col] = bf16rne(av_[ct][r]);
            }
        }
    }
}

// ---------------- GAT edge phase: one wave/node, 8 lanes/edge, bf16 gathers ------
template<bool LAST>
__global__ __launch_bounds__(256) void k_edge(
        const float* __restrict__ q, const unsigned short* __restrict__ karr,
        const unsigned short* __restrict__ varr,
        const int* __restrict__ rowptr,
        const int* __restrict__ esrc,
        float* __restrict__ ecsr,
        float* __restrict__ hout,
        float* __restrict__ signals,
        const float* __restrict__ Wsig, const float* __restrict__ bsig,
        int n) {
    int node = blockIdx.x * 4 + (threadIdx.x >> 6);
    if (node >= n) return;
    int lane = threadIdx.x & 63;
    int li = lane & 7, g = lane >> 3;
    int start = rowptr[node], end = rowptr[node + 1];
    int deg = end - start;
    float qf[8];
    {
        float4 q0 = *reinterpret_cast<const float4*>(q + (size_t)node * HH + li * 8);
        float4 q1 = *reinterpret_cast<const float4*>(q + (size_t)node * HH + li * 8 + 4);
        qf[0] = q0.x; qf[1] = q0.y; qf[2] = q0.z; qf[3] = q0.w;
        qf[4] = q1.x; qf[5] = q1.y; qf[6] = q1.z; qf[7] = q1.w;
    }
    int p0 = start + lane;
    int el = (p0 < end) ? esrc[p0] : 0;   // first 64 source indices in registers

    float acc[8] = {0.f, 0.f, 0.f, 0.f, 0.f, 0.f, 0.f, 0.f};
    float s = 0.f;
    for (int c = 0; c < deg; c += 8) {
        int idx = c + g;
        bool valid = idx < deg;
        int sv;
        if (c < 64) sv = __shfl(el, idx);                 // wave-uniform branch
        else        sv = valid ? esrc[start + idx] : 0;
        ushort8 kv = *reinterpret_cast<const ushort8*>(karr + (size_t)sv * HH + li * 8);
        ushort8 vv = *reinterpret_cast<const ushort8*>(varr + (size_t)sv * HH + li * 8);
        float d = 0.f;
        #pragma unroll
        for (int j = 0; j < 8; ++j) d = fmaf(qf[j], bf16tof(kv[j]), d);
        d += __shfl_xor(d, 1);
        d += __shfl_xor(d, 2);
        d += __shfl_xor(d, 4);
        float e = valid ? __expf(fmaxf(d * 0.125f, 0.f)) : 0.f;
        s += e;
        if (valid && li == 0) ecsr[start + idx] = e;
        #pragma unroll
        for (int j = 0; j < 8; ++j) acc[j] = fmaf(e, bf16tof(vv[j]), acc[j]);
    }
    // combine the 8 groups
    #pragma unroll
    for (int off = 8; off < 64; off <<= 1) {
        s += __shfl_xor(s, off);
        #pragma unroll
        for (int j = 0; j < 8; ++j) acc[j] += __shfl_xor(acc[j], off);
    }
    float inv = 1.0f / (s + 1e-16f);

    if (!LAST) {
        if (g == 0) {
            float4 o0, o1;
            o0.x = gelu_f(acc[0] * inv); o0.y = gelu_f(acc[1] * inv);
            o0.z = gelu_f(acc[2] * inv); o0.w = gelu_f(acc[3] * inv);
            o1.x = gelu_f(acc[4] * inv); o1.y = gelu_f(acc[5] * inv);
            o1.z = gelu_f(acc[6] * inv); o1.w = gelu_f(acc[7] * inv);
            *reinterpret_cast<float4*>(hout + (size_t)node * HH + li * 8)     = o0;
            *reinterpret_cast<float4*>(hout + (size_t)node * HH + li * 8 + 4) = o1;
        }
    } else {
        float4 w0 = *reinterpret_cast<const float4*>(Wsig + li * 8);
        float4 w1 = *reinterpret_cast<const float4*>(Wsig + li * 8 + 4);
        float t = acc[0] * w0.x + acc[1] * w0.y + acc[2] * w0.z + acc[3] * w0.w
                + acc[4] * w1.x + acc[5] * w1.y + acc[6] * w1.z + acc[7] * w1.w;
        t *= inv;
        t += __shfl_xor(t, 1);
        t += __shfl_xor(t, 2);
        t += __shfl_xor(t, 4);
        if (lane == 0) signals[node] = t + bsig[0];
    }
    // normalize in place (coalesced)
    for (int p = p0; p < end; p += 64)
        ecsr[p] *= inv;
}

extern "C" void kernel_launch(void* const* d_in, const int* in_sizes, int n_in,
                              void* d_out, int out_size, void* d_ws, size_t ws_size,
                              hipStream_t stream) {
    const float* x   = (const float*)d_in[0];
    const int*   ei  = (const int*)  d_in[1];
    const float* Wp  = (const float*)d_in[2];
    const float* bp  = (const float*)d_in[3];
    const float* Wq1 = (const float*)d_in[4];
    const float* Wk1 = (const float*)d_in[5];
    const float* Wv1 = (const float*)d_in[6];
    const float* Wq2 = (const float*)d_in[7];
    const float* Wk2 = (const float*)d_in[8];
    const float* Wv2 = (const float*)d_in[9];
    const float* Wsg = (const float*)d_in[10];
    const float* bsg = (const float*)d_in[11];

    const int N = in_sizes[0] / FF;
    const int E = in_sizes[1] / 2;
    const int* src = ei;
    const int* dst = ei + E;

    char* ws = (char*)d_ws;
    size_t off = 0;
    auto alloc = [&](size_t bytes) -> void* {
        void* p = ws + off;
        off += (bytes + 255) & ~(size_t)255;
        return p;
    };
    float* q          = (float*)alloc((size_t)N * HH * 4);
    unsigned short* kb = (unsigned short*)alloc((size_t)N * HH * 2);
    unsigned short* vb = (unsigned short*)alloc((size_t)N * HH * 2);
    float* h          = (float*)alloc((size_t)N * HH * 4);
    float* ecsr       = (float*)alloc((size_t)E * 4);
    int* inv          = (int*)alloc((size_t)E * 4);
    int* esrc         = (int*)alloc((size_t)E * 4);
    int* deg          = (int*)alloc((size_t)N * 4);
    int* cursor       = (int*)alloc((size_t)N * 4);
    int* rowptr       = (int*)alloc((size_t)(N + 1) * 4);
    int* bsums        = (int*)alloc(256 * 4);
    int* boffs        = (int*)alloc(256 * 4);
    short* wf         = (short*)alloc((size_t)81920 * 2);   // W fragment tables

    float* out     = (float*)d_out;
    float* signals = out;
    float* attn1   = out + N;
    float* attn2   = out + N + E;

    // W fragment prep (independent of CSR)
    k_wprep<<<64, 256, 0, stream>>>(Wp, Wq1, Wk1, Wv1, Wq2, Wk2, Wv2, wf);

    // CSR build
    hipMemsetAsync(deg, 0, (size_t)N * 4, stream);
    int e4Blocks = ((E + 3) / 4 + 255) / 256;
    k_degree<<<e4Blocks, 256, 0, stream>>>(dst, deg, E);
    int nb = (N + 1023) / 1024;
    k_scan1<<<nb, 256, 0, stream>>>(deg, rowptr, bsums, N);
    k_scan2<<<1, 256, 0, stream>>>(bsums, boffs, nb);
    k_scan3<<<(N + 1 + 255) / 256, 256, 0, stream>>>(rowptr, cursor, boffs, N, E);
    k_fill<<<e4Blocks, 256, 0, stream>>>(src, dst, cursor, esrc, inv, E);

    // GEMM grids: 64 rows/block (4 waves x 16 rows)
    int gemmBlocks = (N + 63) / 64;

    // layer 0: projection + gelu
    k_proj<<<gemmBlocks, 256, 0, stream>>>(x, wf, bp, h, N);

    const short* wfbase = wf + 32768;
    // layer 1
    k_qkv<<<gemmBlocks, 256, 0, stream>>>(h, wfbase, wfbase + 8192, wfbase + 16384,
            q, kb, vb, N);
    k_edge<false><<<(N + 3) / 4, 256, 0, stream>>>(q, kb, vb, rowptr, esrc,
            ecsr, h, nullptr, nullptr, nullptr, N);
    k_attn<<<e4Blocks, 256, 0, stream>>>(ecsr, inv, attn1, E);

    // layer 2 (+ fused signal head)
    k_qkv<<<gemmBlocks, 256, 0, stream>>>(h, wfbase + 24576, wfbase + 32768, wfbase + 40960,
            q, kb, vb, N);
    k_edge<true><<<(N + 3) / 4, 256, 0, stream>>>(q, kb, vb, rowptr, esrc,
            ecsr, nullptr, signals, Wsg, bsg, N);
    k_attn<<<e4Blocks, 256, 0, stream>>>(ecsr, inv, attn2, E);
}

// Round 7
// 359.682 us; speedup vs baseline: 1.3211x; 1.3211x over previous
//
#include <hip/hip_runtime.h>
#include <math.h>

#define FF 256
#define HH 64

typedef __attribute__((ext_vector_type(8))) short short8;
typedef __attribute__((ext_vector_type(8))) unsigned short ushort8;
typedef __attribute__((ext_vector_type(4))) float f32x4;

__device__ __forceinline__ float gelu_f(float x) {
    return 0.5f * x * (1.0f + erff(x * 0.70710678118654752f));
}

__device__ __forceinline__ unsigned short bf16rne(float f) {
    unsigned u = __float_as_uint(f);
    unsigned r = u + 0x7FFFu + ((u >> 16) & 1u);
    return (unsigned short)(r >> 16);
}
__device__ __forceinline__ float bf16tof(unsigned short s) {
    return __uint_as_float(((unsigned)s) << 16);
}

// split f into bf16 hi + bf16 lo (RNE)
__device__ __forceinline__ void bf16split(float f, short& hi, short& lo) {
    unsigned u = __float_as_uint(f);
    unsigned r = u + 0x7FFFu + ((u >> 16) & 1u);
    hi = (short)(r >> 16);
    float fh = __uint_as_float(r & 0xFFFF0000u);
    float fl = f - fh;
    unsigned u2 = __float_as_uint(fl);
    unsigned r2 = u2 + 0x7FFFu + ((u2 >> 16) & 1u);
    lo = (short)(r2 >> 16);
}

// ---- W fragment tables in workspace (bf16 hi/lo, fragment-ordered) ----
__global__ __launch_bounds__(256) void k_wprep(
        const float* __restrict__ Wp,
        const float* __restrict__ Wq1, const float* __restrict__ Wk1, const float* __restrict__ Wv1,
        const float* __restrict__ Wq2, const float* __restrict__ Wk2, const float* __restrict__ Wv2,
        short* __restrict__ wf) {
    int total = 16384 + 6 * 4096;
    for (int gid = blockIdx.x * 256 + threadIdx.x; gid < total; gid += gridDim.x * 256) {
        const float* W;
        int fid, hibase, lobase;
        if (gid < 16384) {
            W = Wp; fid = gid; hibase = 0; lobase = 16384;
        } else {
            int t = gid - 16384;
            int m = t >> 12;
            fid = t & 4095;
            switch (m) {
                case 0: W = Wq1; break;
                case 1: W = Wk1; break;
                case 2: W = Wv1; break;
                case 3: W = Wq2; break;
                case 4: W = Wk2; break;
                default: W = Wv2; break;
            }
            hibase = 32768 + m * 8192;
            lobase = hibase + 4096;
        }
        int j    = fid & 7;
        int lane = (fid >> 3) & 63;
        int ct   = (fid >> 9) & 3;
        int s    = fid >> 11;
        int k    = s * 32 + (lane >> 4) * 8 + j;
        int col  = ct * 16 + (lane & 15);
        short hi, lo;
        bf16split(W[k * HH + col], hi, lo);
        wf[hibase + fid] = hi;
        wf[lobase + fid] = lo;
    }
}

// ---------------- CSR build ----------------
// degree count + per-edge rank within its destination bucket
__global__ __launch_bounds__(256) void k_degree(const int* __restrict__ dst,
        int* __restrict__ deg, int* __restrict__ rank, int E) {
    int e0 = (blockIdx.x * 256 + threadIdx.x) * 4;
    if (e0 + 3 < E) {
        int4 d4 = *reinterpret_cast<const int4*>(dst + e0);
        int4 r4;
        r4.x = atomicAdd(&deg[d4.x], 1);
        r4.y = atomicAdd(&deg[d4.y], 1);
        r4.z = atomicAdd(&deg[d4.z], 1);
        r4.w = atomicAdd(&deg[d4.w], 1);
        *reinterpret_cast<int4*>(rank + e0) = r4;
    } else {
        for (int e = e0; e < E; ++e) rank[e] = atomicAdd(&deg[dst[e]], 1);
    }
}

__global__ __launch_bounds__(256) void k_scan1(const int* __restrict__ deg,
        int* __restrict__ out, int* __restrict__ bsums, int n) {
    __shared__ int lds[256];
    int t = threadIdx.x;
    int base = blockIdx.x * 1024 + t * 4;
    int v0 = (base     < n) ? deg[base]     : 0;
    int v1 = (base + 1 < n) ? deg[base + 1] : 0;
    int v2 = (base + 2 < n) ? deg[base + 2] : 0;
    int v3 = (base + 3 < n) ? deg[base + 3] : 0;
    int s = v0 + v1 + v2 + v3;
    int val = s;
    lds[t] = val;
    __syncthreads();
    #pragma unroll
    for (int off = 1; off < 256; off <<= 1) {
        int tmp = (t >= off) ? lds[t - off] : 0;
        __syncthreads();
        val += tmp;
        lds[t] = val;
        __syncthreads();
    }
    if (t == 255) bsums[blockIdx.x] = val;
    int excl = val - s;
    if (base     < n) out[base]     = excl;
    if (base + 1 < n) out[base + 1] = excl + v0;
    if (base + 2 < n) out[base + 2] = excl + v0 + v1;
    if (base + 3 < n) out[base + 3] = excl + v0 + v1 + v2;
}

__global__ __launch_bounds__(256) void k_scan2(const int* __restrict__ bsums,
        int* __restrict__ boffs, int nb) {
    __shared__ int lds[256];
    int t = threadIdx.x;
    int s = (t < nb) ? bsums[t] : 0;
    int val = s;
    lds[t] = val;
    __syncthreads();
    #pragma unroll
    for (int off = 1; off < 256; off <<= 1) {
        int tmp = (t >= off) ? lds[t - off] : 0;
        __syncthreads();
        val += tmp;
        lds[t] = val;
        __syncthreads();
    }
    if (t < nb) boffs[t] = val - s;
}

__global__ __launch_bounds__(256) void k_scan3(int* __restrict__ rowptr,
        const int* __restrict__ boffs, int n, int E) {
    int i = blockIdx.x * 256 + threadIdx.x;
    if (i < n) rowptr[i] += boffs[i >> 10];
    if (i == n) rowptr[n] = E;
}

// fill: atomic-free; pos = rowptr[dst] (L2-resident gather) + rank (coalesced)
__global__ __launch_bounds__(256) void k_fill(const int* __restrict__ src,
        const int* __restrict__ dst, const int* __restrict__ rowptr,
        const int* __restrict__ rank,
        int* __restrict__ esrc, int* __restrict__ inv, int E) {
    int e0 = (blockIdx.x * 256 + threadIdx.x) * 4;
    if (e0 + 3 < E) {
        int4 d4 = *reinterpret_cast<const int4*>(dst + e0);
        int4 s4 = *reinterpret_cast<const int4*>(src + e0);
        int4 r4 = *reinterpret_cast<const int4*>(rank + e0);
        int p0 = rowptr[d4.x] + r4.x;
        int p1 = rowptr[d4.y] + r4.y;
        int p2 = rowptr[d4.z] + r4.z;
        int p3 = rowptr[d4.w] + r4.w;
        esrc[p0] = s4.x;
        esrc[p1] = s4.y;
        esrc[p2] = s4.z;
        esrc[p3] = s4.w;
        *reinterpret_cast<int4*>(inv + e0) = (int4){p0, p1, p2, p3};
    } else {
        for (int e = e0; e < E; ++e) {
            int pos = rowptr[dst[e]] + rank[e];
            esrc[pos] = src[e];
            inv[e] = pos;
        }
    }
}

// edge-order attention coefficients: coalesced write, gathered read
__global__ __launch_bounds__(256) void k_attn(const float* __restrict__ ecsr,
        const int* __restrict__ inv, float* __restrict__ attn, int E) {
    int e0 = (blockIdx.x * 256 + threadIdx.x) * 4;
    if (e0 + 3 < E) {
        int4 i4 = *reinterpret_cast<const int4*>(inv + e0);
        float4 a;
        a.x = ecsr[i4.x]; a.y = ecsr[i4.y]; a.z = ecsr[i4.z]; a.w = ecsr[i4.w];
        *reinterpret_cast<float4*>(attn + e0) = a;
    } else {
        for (int e = e0; e < E; ++e) attn[e] = ecsr[inv[e]];
    }
}

// ---------------- proj GEMM + gelu via MFMA (split-bf16, 3 terms) ----------------
__global__ __launch_bounds__(256) void k_proj(const float* __restrict__ x,
        const short* __restrict__ wf, const float* __restrict__ b,
        float* __restrict__ h, int n) {
    int lane = threadIdx.x & 63;
    int w    = threadIdx.x >> 6;
    int m    = lane & 15, g = lane >> 4;
    int rowc = min(blockIdx.x * 64 + w * 16 + m, n - 1);
    const float* xrow = x + (size_t)rowc * FF + g * 8;
    const short* wlo = wf + 16384;
    f32x4 acc[4];
    #pragma unroll
    for (int ct = 0; ct < 4; ++ct) acc[ct] = (f32x4){0.f, 0.f, 0.f, 0.f};
    #pragma unroll
    for (int s = 0; s < 8; ++s) {
        float4 a0 = *reinterpret_cast<const float4*>(xrow + s * 32);
        float4 a1 = *reinterpret_cast<const float4*>(xrow + s * 32 + 4);
        float av[8] = {a0.x, a0.y, a0.z, a0.w, a1.x, a1.y, a1.z, a1.w};
        short8 ah, al;
        #pragma unroll
        for (int j = 0; j < 8; ++j) { short hi, lo; bf16split(av[j], hi, lo); ah[j] = hi; al[j] = lo; }
        #pragma unroll
        for (int ct = 0; ct < 4; ++ct) {
            int fo = ((s * 4 + ct) * 64 + lane) * 8;
            short8 bh = *reinterpret_cast<const short8*>(wf + fo);
            short8 bl = *reinterpret_cast<const short8*>(wlo + fo);
            acc[ct] = __builtin_amdgcn_mfma_f32_16x16x32_bf16(ah, bh, acc[ct], 0, 0, 0);
            acc[ct] = __builtin_amdgcn_mfma_f32_16x16x32_bf16(al, bh, acc[ct], 0, 0, 0);
            acc[ct] = __builtin_amdgcn_mfma_f32_16x16x32_bf16(ah, bl, acc[ct], 0, 0, 0);
        }
    }
    int orow0 = blockIdx.x * 64 + w * 16 + g * 4;
    #pragma unroll
    for (int ct = 0; ct < 4; ++ct) {
        int col = ct * 16 + m;
        float bias = b[col];
        #pragma unroll
        for (int r = 0; r < 4; ++r) {
            int row = orow0 + r;
            if (row < n) h[(size_t)row * HH + col] = gelu_f(acc[ct][r] + bias);
        }
    }
}

// ---------------- fused QKV GEMM via MFMA; k,v written interleaved bf16 ----------
// kv row layout (128 ushorts): block b=c>>3 : k[c] at b*16+(c&7), v[c] at b*16+8+(c&7)
__global__ __launch_bounds__(256) void k_qkv(const float* __restrict__ hsrc,
        const short* __restrict__ wfq, const short* __restrict__ wfk, const short* __restrict__ wfv,
        float* __restrict__ q, unsigned short* __restrict__ kv, int n) {
    int lane = threadIdx.x & 63;
    int w    = threadIdx.x >> 6;
    int m    = lane & 15, g = lane >> 4;
    int rowc = min(blockIdx.x * 64 + w * 16 + m, n - 1);
    const float* hrow = hsrc + (size_t)rowc * HH + g * 8;
    f32x4 aq[4], ak[4], av_[4];
    #pragma unroll
    for (int ct = 0; ct < 4; ++ct) {
        aq[ct] = (f32x4){0.f, 0.f, 0.f, 0.f};
        ak[ct] = (f32x4){0.f, 0.f, 0.f, 0.f};
        av_[ct] = (f32x4){0.f, 0.f, 0.f, 0.f};
    }
    #pragma unroll
    for (int s = 0; s < 2; ++s) {
        float4 a0 = *reinterpret_cast<const float4*>(hrow + s * 32);
        float4 a1 = *reinterpret_cast<const float4*>(hrow + s * 32 + 4);
        float avv[8] = {a0.x, a0.y, a0.z, a0.w, a1.x, a1.y, a1.z, a1.w};
        short8 ah, al;
        #pragma unroll
        for (int j = 0; j < 8; ++j) { short hi, lo; bf16split(avv[j], hi, lo); ah[j] = hi; al[j] = lo; }
        #pragma unroll
        for (int ct = 0; ct < 4; ++ct) {
            int fo = ((s * 4 + ct) * 64 + lane) * 8;
            short8 qh = *reinterpret_cast<const short8*>(wfq + fo);
            short8 ql = *reinterpret_cast<const short8*>(wfq + 4096 + fo);
            short8 kh = *reinterpret_cast<const short8*>(wfk + fo);
            short8 kl = *reinterpret_cast<const short8*>(wfk + 4096 + fo);
            short8 vh = *reinterpret_cast<const short8*>(wfv + fo);
            short8 vl = *reinterpret_cast<const short8*>(wfv + 4096 + fo);
            aq[ct] = __builtin_amdgcn_mfma_f32_16x16x32_bf16(ah, qh, aq[ct], 0, 0, 0);
            aq[ct] = __builtin_amdgcn_mfma_f32_16x16x32_bf16(al, qh, aq[ct], 0, 0, 0);
            aq[ct] = __builtin_amdgcn_mfma_f32_16x16x32_bf16(ah, ql, aq[ct], 0, 0, 0);
            ak[ct] = __builtin_amdgcn_mfma_f32_16x16x32_bf16(ah, kh, ak[ct], 0, 0, 0);
            ak[ct] = __builtin_amdgcn_mfma_f32_16x16x32_bf16(al, kh, ak[ct], 0, 0, 0);
            ak[ct] = __builtin_amdgcn_mfma_f32_16x16x32_bf16(ah, kl, ak[ct], 0, 0, 0);
            av_[ct] = __builtin_amdgcn_mfma_f32_16x16x32_bf16(ah, vh, av_[ct], 0, 0, 0);
            av_[ct] = __builtin_amdgcn_mfma_f32_16x16x32_bf16(al, vh, av_[ct], 0, 0, 0);
            av_[ct] = __builtin_amdgcn_mfma_f32_16x16x32_bf16(ah, vl, av_[ct], 0, 0, 0);
        }
    }
    int orow0 = blockIdx.x * 64 + w * 16 + g * 4;
    #pragma unroll
    for (int ct = 0; ct < 4; ++ct) {
        int col = ct * 16 + m;
        int cb  = (col >> 3) * 16 + (col & 7);
        #pragma unroll
        for (int r = 0; r < 4; ++r) {
            int row = orow0 + r;
            if (row < n) {
                q[(size_t)row * HH + col]       = aq[ct][r];
                kv[(size_t)row * 128 + cb]      = bf16rne(ak[ct][r]);
                kv[(size_t)row * 128 + cb + 8]  = bf16rne(av_[ct][r]);
            }
        }
    }
}

// ---------------- GAT edge phase: one wave/node, 8 lanes/edge, 2x unrolled ------
template<bool LAST>
__global__ __launch_bounds__(256) void k_edge(
        const float* __restrict__ q, const unsigned short* __restrict__ kv,
        const int* __restrict__ rowptr,
        const int* __restrict__ esrc,
        float* __restrict__ ecsr,
        float* __restrict__ hout,
        float* __restrict__ signals,
        const float* __restrict__ Wsig, const float* __restrict__ bsig,
        int n) {
    int node = blockIdx.x * 4 + (threadIdx.x >> 6);
    if (node >= n) return;
    int lane = threadIdx.x & 63;
    int li = lane & 7, g = lane >> 3;
    int start = rowptr[node], end = rowptr[node + 1];
    int deg = end - start;
    float qf[8];
    {
        float4 q0 = *reinterpret_cast<const float4*>(q + (size_t)node * HH + li * 8);
        float4 q1 = *reinterpret_cast<const float4*>(q + (size_t)node * HH + li * 8 + 4);
        qf[0] = q0.x; qf[1] = q0.y; qf[2] = q0.z; qf[3] = q0.w;
        qf[4] = q1.x; qf[5] = q1.y; qf[6] = q1.z; qf[7] = q1.w;
    }
    int p0 = start + lane;
    int el = (p0 < end) ? esrc[p0] : 0;   // first 64 source indices in registers

    float acc[8] = {0.f, 0.f, 0.f, 0.f, 0.f, 0.f, 0.f, 0.f};
    float s = 0.f;
    for (int c = 0; c < deg; c += 16) {
        int idx0 = c + g, idx1 = c + 8 + g;
        bool v0 = idx0 < deg, v1 = idx1 < deg;
        int sv0, sv1;
        if (c + 16 <= 64) {
            sv0 = __shfl(el, idx0);
            sv1 = __shfl(el, idx1);
        } else {
            sv0 = v0 ? esrc[start + idx0] : 0;
            sv1 = v1 ? esrc[start + idx1] : 0;
        }
        const unsigned short* b0 = kv + (size_t)sv0 * 128 + li * 16;
        const unsigned short* b1 = kv + (size_t)sv1 * 128 + li * 16;
        ushort8 k0 = *reinterpret_cast<const ushort8*>(b0);
        ushort8 w0 = *reinterpret_cast<const ushort8*>(b0 + 8);
        ushort8 k1 = *reinterpret_cast<const ushort8*>(b1);
        ushort8 w1 = *reinterpret_cast<const ushort8*>(b1 + 8);
        float d0 = 0.f, d1 = 0.f;
        #pragma unroll
        for (int j = 0; j < 8; ++j) {
            d0 = fmaf(qf[j], bf16tof(k0[j]), d0);
            d1 = fmaf(qf[j], bf16tof(k1[j]), d1);
        }
        d0 += __shfl_xor(d0, 1); d1 += __shfl_xor(d1, 1);
        d0 += __shfl_xor(d0, 2); d1 += __shfl_xor(d1, 2);
        d0 += __shfl_xor(d0, 4); d1 += __shfl_xor(d1, 4);
        float e0 = v0 ? __expf(fmaxf(d0 * 0.125f, 0.f)) : 0.f;
        float e1 = v1 ? __expf(fmaxf(d1 * 0.125f, 0.f)) : 0.f;
        s += e0 + e1;
        if (v0 && li == 0) ecsr[start + idx0] = e0;
        if (v1 && li == 0) ecsr[start + idx1] = e1;
        #pragma unroll
        for (int j = 0; j < 8; ++j) {
            acc[j] = fmaf(e0, bf16tof(w0[j]), acc[j]);
            acc[j] = fmaf(e1, bf16tof(w1[j]), acc[j]);
        }
    }
    // combine the 8 groups
    #pragma unroll
    for (int off = 8; off < 64; off <<= 1) {
        s += __shfl_xor(s, off);
        #pragma unroll
        for (int j = 0; j < 8; ++j) acc[j] += __shfl_xor(acc[j], off);
    }
    float inv = 1.0f / (s + 1e-16f);

    if (!LAST) {
        if (g == 0) {
            float4 o0, o1;
            o0.x = gelu_f(acc[0] * inv); o0.y = gelu_f(acc[1] * inv);
            o0.z = gelu_f(acc[2] * inv); o0.w = gelu_f(acc[3] * inv);
            o1.x = gelu_f(acc[4] * inv); o1.y = gelu_f(acc[5] * inv);
            o1.z = gelu_f(acc[6] * inv); o1.w = gelu_f(acc[7] * inv);
            *reinterpret_cast<float4*>(hout + (size_t)node * HH + li * 8)     = o0;
            *reinterpret_cast<float4*>(hout + (size_t)node * HH + li * 8 + 4) = o1;
        }
    } else {
        float4 w0 = *reinterpret_cast<const float4*>(Wsig + li * 8);
        float4 w1 = *reinterpret_cast<const float4*>(Wsig + li * 8 + 4);
        float t = acc[0] * w0.x + acc[1] * w0.y + acc[2] * w0.z + acc[3] * w0.w
                + acc[4] * w1.x + acc[5] * w1.y + acc[6] * w1.z + acc[7] * w1.w;
        t *= inv;
        t += __shfl_xor(t, 1);
        t += __shfl_xor(t, 2);
        t += __shfl_xor(t, 4);
        if (lane == 0) signals[node] = t + bsig[0];
    }
    // normalize in place (coalesced)
    for (int p = p0; p < end; p += 64)
        ecsr[p] *= inv;
}

extern "C" void kernel_launch(void* const* d_in, const int* in_sizes, int n_in,
                              void* d_out, int out_size, void* d_ws, size_t ws_size,
                              hipStream_t stream) {
    const float* x   = (const float*)d_in[0];
    const int*   ei  = (const int*)  d_in[1];
    const float* Wp  = (const float*)d_in[2];
    const float* bp  = (const float*)d_in[3];
    const float* Wq1 = (const float*)d_in[4];
    const float* Wk1 = (const float*)d_in[5];
    const float* Wv1 = (const float*)d_in[6];
    const float* Wq2 = (const float*)d_in[7];
    const float* Wk2 = (const float*)d_in[8];
    const float* Wv2 = (const float*)d_in[9];
    const float* Wsg = (const float*)d_in[10];
    const float* bsg = (const float*)d_in[11];

    const int N = in_sizes[0] / FF;
    const int E = in_sizes[1] / 2;
    const int* src = ei;
    const int* dst = ei + E;

    char* ws = (char*)d_ws;
    size_t off = 0;
    auto alloc = [&](size_t bytes) -> void* {
        void* p = ws + off;
        off += (bytes + 255) & ~(size_t)255;
        return p;
    };
    float* q           = (float*)alloc((size_t)N * HH * 4);
    unsigned short* kv = (unsigned short*)alloc((size_t)N * 128 * 2);
    float* h           = (float*)alloc((size_t)N * HH * 4);
    float* ecsr        = (float*)alloc((size_t)E * 4);
    int* inv           = (int*)alloc((size_t)E * 4);
    int* esrc          = (int*)alloc((size_t)E * 4);
    int* rank          = (int*)alloc((size_t)E * 4);
    int* deg           = (int*)alloc((size_t)N * 4);
    int* rowptr        = (int*)alloc((size_t)(N + 1) * 4);
    int* bsums         = (int*)alloc(256 * 4);
    int* boffs         = (int*)alloc(256 * 4);
    short* wf          = (short*)alloc((size_t)81920 * 2);   // W fragment tables

    float* out     = (float*)d_out;
    float* signals = out;
    float* attn1   = out + N;
    float* attn2   = out + N + E;

    // W fragment prep (independent of CSR)
    k_wprep<<<64, 256, 0, stream>>>(Wp, Wq1, Wk1, Wv1, Wq2, Wk2, Wv2, wf);

    // CSR build
    hipMemsetAsync(deg, 0, (size_t)N * 4, stream);
    int e4Blocks = ((E + 3) / 4 + 255) / 256;
    k_degree<<<e4Blocks, 256, 0, stream>>>(dst, deg, rank, E);
    int nb = (N + 1023) / 1024;
    k_scan1<<<nb, 256, 0, stream>>>(deg, rowptr, bsums, N);
    k_scan2<<<1, 256, 0, stream>>>(bsums, boffs, nb);
    k_scan3<<<(N + 1 + 255) / 256, 256, 0, stream>>>(rowptr, boffs, N, E);
    k_fill<<<e4Blocks, 256, 0, stream>>>(src, dst, rowptr, rank, esrc, inv, E);

    // GEMM grids: 64 rows/block (4 waves x 16 rows)
    int gemmBlocks = (N + 63) / 64;

    // layer 0: projection + gelu
    k_proj<<<gemmBlocks, 256, 0, stream>>>(x, wf, bp, h, N);

    const short* wfbase = wf + 32768;
    // layer 1
    k_qkv<<<gemmBlocks, 256, 0, stream>>>(h, wfbase, wfbase + 8192, wfbase + 16384,
            q, kv, N);
    k_edge<false><<<(N + 3) / 4, 256, 0, stream>>>(q, kv, rowptr, esrc,
            ecsr, h, nullptr, nullptr, nullptr, N);
    k_attn<<<e4Blocks, 256, 0, stream>>>(ecsr, inv, attn1, E);

    // layer 2 (+ fused signal head)
    k_qkv<<<gemmBlocks, 256, 0, stream>>>(h, wfbase + 24576, wfbase + 32768, wfbase + 40960,
            q, kv, N);
    k_edge<true><<<(N + 3) / 4, 256, 0, stream>>>(q, kv, rowptr, esrc,
            ecsr, nullptr, signals, Wsg, bsg, N);
    k_attn<<<e4Blocks, 256, 0, stream>>>(ecsr, inv, attn2, E);
}

// Round 8
// 341.495 us; speedup vs baseline: 1.3915x; 1.0533x over previous
//
#include <hip/hip_runtime.h>
#include <hip/hip_fp16.h>
#include <math.h>

#define FF 256
#define HH 64

typedef __attribute__((ext_vector_type(8))) short short8;
typedef __attribute__((ext_vector_type(4))) float f32x4;

// cheap gelu: A&S 7.1.26 erf approximation, |err| <= 1.5e-7
__device__ __forceinline__ float gelu_f(float x) {
    float ax = fabsf(x) * 0.70710678118654752f;
    float t = __builtin_amdgcn_rcpf(fmaf(0.3275911f, ax, 1.0f));
    float poly = t * fmaf(t, fmaf(t, fmaf(t, fmaf(t, 1.061405429f, -1.453152027f),
                  1.421413741f), -0.284496736f), 0.254829592f);
    float er = 1.0f - poly * __expf(-ax * ax);
    er = (x < 0.f) ? -er : er;
    return 0.5f * x * (1.0f + er);
}

__device__ __forceinline__ unsigned short bf16rne(float f) {
    unsigned u = __float_as_uint(f);
    unsigned r = u + 0x7FFFu + ((u >> 16) & 1u);
    return (unsigned short)(r >> 16);
}

// split f into bf16 hi + bf16 lo (RNE)
__device__ __forceinline__ void bf16split(float f, short& hi, short& lo) {
    unsigned u = __float_as_uint(f);
    unsigned r = u + 0x7FFFu + ((u >> 16) & 1u);
    hi = (short)(r >> 16);
    float fh = __uint_as_float(r & 0xFFFF0000u);
    float fl = f - fh;
    unsigned u2 = __float_as_uint(fl);
    unsigned r2 = u2 + 0x7FFFu + ((u2 >> 16) & 1u);
    lo = (short)(r2 >> 16);
}

__device__ __forceinline__ __half2 shfl_xor_h2(__half2 v, int off) {
    union { __half2 h; int i; } u;
    u.h = v;
    u.i = __shfl_xor(u.i, off, 64);
    return u.h;
}

// ---- W fragment tables in workspace (bf16 hi/lo, fragment-ordered) ----
__global__ __launch_bounds__(256) void k_wprep(
        const float* __restrict__ Wp,
        const float* __restrict__ Wq1, const float* __restrict__ Wk1, const float* __restrict__ Wv1,
        const float* __restrict__ Wq2, const float* __restrict__ Wk2, const float* __restrict__ Wv2,
        short* __restrict__ wf) {
    int total = 16384 + 6 * 4096;
    for (int gid = blockIdx.x * 256 + threadIdx.x; gid < total; gid += gridDim.x * 256) {
        const float* W;
        int fid, hibase, lobase;
        if (gid < 16384) {
            W = Wp; fid = gid; hibase = 0; lobase = 16384;
        } else {
            int t = gid - 16384;
            int m = t >> 12;
            fid = t & 4095;
            switch (m) {
                case 0: W = Wq1; break;
                case 1: W = Wk1; break;
                case 2: W = Wv1; break;
                case 3: W = Wq2; break;
                case 4: W = Wk2; break;
                default: W = Wv2; break;
            }
            hibase = 32768 + m * 8192;
            lobase = hibase + 4096;
        }
        int j    = fid & 7;
        int lane = (fid >> 3) & 63;
        int ct   = (fid >> 9) & 3;
        int s    = fid >> 11;
        int k    = s * 32 + (lane >> 4) * 8 + j;
        int col  = ct * 16 + (lane & 15);
        short hi, lo;
        bf16split(W[k * HH + col], hi, lo);
        wf[hibase + fid] = hi;
        wf[lobase + fid] = lo;
    }
}

// ---------------- CSR build ----------------
__global__ __launch_bounds__(256) void k_degree(const int* __restrict__ dst,
        int* __restrict__ deg, int* __restrict__ rank, int E) {
    int e0 = (blockIdx.x * 256 + threadIdx.x) * 4;
    if (e0 + 3 < E) {
        int4 d4 = *reinterpret_cast<const int4*>(dst + e0);
        int4 r4;
        r4.x = atomicAdd(&deg[d4.x], 1);
        r4.y = atomicAdd(&deg[d4.y], 1);
        r4.z = atomicAdd(&deg[d4.z], 1);
        r4.w = atomicAdd(&deg[d4.w], 1);
        *reinterpret_cast<int4*>(rank + e0) = r4;
    } else {
        for (int e = e0; e < E; ++e) rank[e] = atomicAdd(&deg[dst[e]], 1);
    }
}

__global__ __launch_bounds__(256) void k_scan1(const int* __restrict__ deg,
        int* __restrict__ out, int* __restrict__ bsums, int n) {
    __shared__ int lds[256];
    int t = threadIdx.x;
    int base = blockIdx.x * 1024 + t * 4;
    int v0 = (base     < n) ? deg[base]     : 0;
    int v1 = (base + 1 < n) ? deg[base + 1] : 0;
    int v2 = (base + 2 < n) ? deg[base + 2] : 0;
    int v3 = (base + 3 < n) ? deg[base + 3] : 0;
    int s = v0 + v1 + v2 + v3;
    int val = s;
    lds[t] = val;
    __syncthreads();
    #pragma unroll
    for (int off = 1; off < 256; off <<= 1) {
        int tmp = (t >= off) ? lds[t - off] : 0;
        __syncthreads();
        val += tmp;
        lds[t] = val;
        __syncthreads();
    }
    if (t == 255) bsums[blockIdx.x] = val;
    int excl = val - s;
    if (base     < n) out[base]     = excl;
    if (base + 1 < n) out[base + 1] = excl + v0;
    if (base + 2 < n) out[base + 2] = excl + v0 + v1;
    if (base + 3 < n) out[base + 3] = excl + v0 + v1 + v2;
}

__global__ __launch_bounds__(256) void k_scan2(const int* __restrict__ bsums,
        int* __restrict__ boffs, int nb) {
    __shared__ int lds[256];
    int t = threadIdx.x;
    int s = (t < nb) ? bsums[t] : 0;
    int val = s;
    lds[t] = val;
    __syncthreads();
    #pragma unroll
    for (int off = 1; off < 256; off <<= 1) {
        int tmp = (t >= off) ? lds[t - off] : 0;
        __syncthreads();
        val += tmp;
        lds[t] = val;
        __syncthreads();
    }
    if (t < nb) boffs[t] = val - s;
}

__global__ __launch_bounds__(256) void k_scan3(int* __restrict__ rowptr,
        const int* __restrict__ boffs, int n, int E) {
    int i = blockIdx.x * 256 + threadIdx.x;
    if (i < n) rowptr[i] += boffs[i >> 10];
    if (i == n) rowptr[n] = E;
}

// fill: atomic-free; pos = rowptr[dst] (L2-resident gather) + rank (coalesced)
__global__ __launch_bounds__(256) void k_fill(const int* __restrict__ src,
        const int* __restrict__ dst, const int* __restrict__ rowptr,
        const int* __restrict__ rank,
        int* __restrict__ esrc, int* __restrict__ inv, int E) {
    int e0 = (blockIdx.x * 256 + threadIdx.x) * 4;
    if (e0 + 3 < E) {
        int4 d4 = *reinterpret_cast<const int4*>(dst + e0);
        int4 s4 = *reinterpret_cast<const int4*>(src + e0);
        int4 r4 = *reinterpret_cast<const int4*>(rank + e0);
        int p0 = rowptr[d4.x] + r4.x;
        int p1 = rowptr[d4.y] + r4.y;
        int p2 = rowptr[d4.z] + r4.z;
        int p3 = rowptr[d4.w] + r4.w;
        esrc[p0] = s4.x;
        esrc[p1] = s4.y;
        esrc[p2] = s4.z;
        esrc[p3] = s4.w;
        *reinterpret_cast<int4*>(inv + e0) = (int4){p0, p1, p2, p3};
    } else {
        for (int e = e0; e < E; ++e) {
            int pos = rowptr[dst[e]] + rank[e];
            esrc[pos] = src[e];
            inv[e] = pos;
        }
    }
}

// edge-order attention coefficients: coalesced write, gathered read
__global__ __launch_bounds__(256) void k_attn(const float* __restrict__ ecsr,
        const int* __restrict__ inv, float* __restrict__ attn, int E) {
    int e0 = (blockIdx.x * 256 + threadIdx.x) * 4;
    if (e0 + 3 < E) {
        int4 i4 = *reinterpret_cast<const int4*>(inv + e0);
        float4 a;
        a.x = ecsr[i4.x]; a.y = ecsr[i4.y]; a.z = ecsr[i4.z]; a.w = ecsr[i4.w];
        *reinterpret_cast<float4*>(attn + e0) = a;
    } else {
        for (int e = e0; e < E; ++e) attn[e] = ecsr[inv[e]];
    }
}

// ---------------- proj GEMM via MFMA (split-bf16, 3 terms); raw output --------
__global__ __launch_bounds__(256) void k_proj(const float* __restrict__ x,
        const short* __restrict__ wf, const float* __restrict__ b,
        float* __restrict__ h, int n) {
    int lane = threadIdx.x & 63;
    int w    = threadIdx.x >> 6;
    int m    = lane & 15, g = lane >> 4;
    int rowc = min(blockIdx.x * 64 + w * 16 + m, n - 1);
    const float* xrow = x + (size_t)rowc * FF + g * 8;
    const short* wlo = wf + 16384;
    f32x4 acc[4];
    #pragma unroll
    for (int ct = 0; ct < 4; ++ct) acc[ct] = (f32x4){0.f, 0.f, 0.f, 0.f};
    #pragma unroll
    for (int s = 0; s < 8; ++s) {
        float4 a0 = *reinterpret_cast<const float4*>(xrow + s * 32);
        float4 a1 = *reinterpret_cast<const float4*>(xrow + s * 32 + 4);
        float av[8] = {a0.x, a0.y, a0.z, a0.w, a1.x, a1.y, a1.z, a1.w};
        short8 ah, al;
        #pragma unroll
        for (int j = 0; j < 8; ++j) { short hi, lo; bf16split(av[j], hi, lo); ah[j] = hi; al[j] = lo; }
        #pragma unroll
        for (int ct = 0; ct < 4; ++ct) {
            int fo = ((s * 4 + ct) * 64 + lane) * 8;
            short8 bh = *reinterpret_cast<const short8*>(wf + fo);
            short8 bl = *reinterpret_cast<const short8*>(wlo + fo);
            acc[ct] = __builtin_amdgcn_mfma_f32_16x16x32_bf16(ah, bh, acc[ct], 0, 0, 0);
            acc[ct] = __builtin_amdgcn_mfma_f32_16x16x32_bf16(al, bh, acc[ct], 0, 0, 0);
            acc[ct] = __builtin_amdgcn_mfma_f32_16x16x32_bf16(ah, bl, acc[ct], 0, 0, 0);
        }
    }
    int orow0 = blockIdx.x * 64 + w * 16 + g * 4;
    #pragma unroll
    for (int ct = 0; ct < 4; ++ct) {
        int col = ct * 16 + m;
        float bias = b[col];
        #pragma unroll
        for (int r = 0; r < 4; ++r) {
            int row = orow0 + r;
            if (row < n) h[(size_t)row * HH + col] = acc[ct][r] + bias;   // raw; gelu in k_qkv
        }
    }
}

// ---------------- fused QKV GEMM via MFMA; gelu on load; f16 outputs ----------
// kv row layout (128 halves): block b=c>>3 : k[c] at b*16+(c&7), v[c] at b*16+8+(c&7)
__global__ __launch_bounds__(256) void k_qkv(const float* __restrict__ hsrc,
        const short* __restrict__ wfq, const short* __restrict__ wfk, const short* __restrict__ wfv,
        __half* __restrict__ qh, __half* __restrict__ kv, int n) {
    int lane = threadIdx.x & 63;
    int w    = threadIdx.x >> 6;
    int m    = lane & 15, g = lane >> 4;
    int rowc = min(blockIdx.x * 64 + w * 16 + m, n - 1);
    const float* hrow = hsrc + (size_t)rowc * HH + g * 8;
    f32x4 aq[4], ak[4], av_[4];
    #pragma unroll
    for (int ct = 0; ct < 4; ++ct) {
        aq[ct] = (f32x4){0.f, 0.f, 0.f, 0.f};
        ak[ct] = (f32x4){0.f, 0.f, 0.f, 0.f};
        av_[ct] = (f32x4){0.f, 0.f, 0.f, 0.f};
    }
    #pragma unroll
    for (int s = 0; s < 2; ++s) {
        float4 a0 = *reinterpret_cast<const float4*>(hrow + s * 32);
        float4 a1 = *reinterpret_cast<const float4*>(hrow + s * 32 + 4);
        float avv[8] = {a0.x, a0.y, a0.z, a0.w, a1.x, a1.y, a1.z, a1.w};
        short8 ah;
        #pragma unroll
        for (int j = 0; j < 8; ++j) ah[j] = (short)bf16rne(gelu_f(avv[j]));
        #pragma unroll
        for (int ct = 0; ct < 4; ++ct) {
            int fo = ((s * 4 + ct) * 64 + lane) * 8;
            short8 qh8 = *reinterpret_cast<const short8*>(wfq + fo);
            short8 ql8 = *reinterpret_cast<const short8*>(wfq + 4096 + fo);
            short8 kh8 = *reinterpret_cast<const short8*>(wfk + fo);
            short8 kl8 = *reinterpret_cast<const short8*>(wfk + 4096 + fo);
            short8 vh8 = *reinterpret_cast<const short8*>(wfv + fo);
            short8 vl8 = *reinterpret_cast<const short8*>(wfv + 4096 + fo);
            aq[ct] = __builtin_amdgcn_mfma_f32_16x16x32_bf16(ah, qh8, aq[ct], 0, 0, 0);
            aq[ct] = __builtin_amdgcn_mfma_f32_16x16x32_bf16(ah, ql8, aq[ct], 0, 0, 0);
            ak[ct] = __builtin_amdgcn_mfma_f32_16x16x32_bf16(ah, kh8, ak[ct], 0, 0, 0);
            ak[ct] = __builtin_amdgcn_mfma_f32_16x16x32_bf16(ah, kl8, ak[ct], 0, 0, 0);
            av_[ct] = __builtin_amdgcn_mfma_f32_16x16x32_bf16(ah, vh8, av_[ct], 0, 0, 0);
            av_[ct] = __builtin_amdgcn_mfma_f32_16x16x32_bf16(ah, vl8, av_[ct], 0, 0, 0);
        }
    }
    int orow0 = blockIdx.x * 64 + w * 16 + g * 4;
    #pragma unroll
    for (int ct = 0; ct < 4; ++ct) {
        int col = ct * 16 + m;
        int cb  = (col >> 3) * 16 + (col & 7);
        #pragma unroll
        for (int r = 0; r < 4; ++r) {
            int row = orow0 + r;
            if (row < n) {
                qh[(size_t)row * HH + col]     = __float2half(aq[ct][r]);
                kv[(size_t)row * 128 + cb]     = __float2half(ak[ct][r]);
                kv[(size_t)row * 128 + cb + 8] = __float2half(av_[ct][r]);
            }
        }
    }
}

// ---------------- GAT edge phase: one wave/node, 8 lanes/edge, f16 packed math ----
template<bool LAST>
__global__ __launch_bounds__(256) void k_edge(
        const __half* __restrict__ qarr, const __half* __restrict__ kv,
        const int* __restrict__ rowptr,
        const int* __restrict__ esrc,
        float* __restrict__ ecsr,
        float* __restrict__ hout,
        float* __restrict__ signals,
        const float* __restrict__ Wsig, const float* __restrict__ bsig,
        int n) {
    int node = blockIdx.x * 4 + (threadIdx.x >> 6);
    if (node >= n) return;
    int lane = threadIdx.x & 63;
    int li = lane & 7, g = lane >> 3;
    int start = rowptr[node], end = rowptr[node + 1];
    int deg = end - start;
    __half2 q2[4];
    {
        union { uint4 u; __half2 h[4]; } Q;
        Q.u = *reinterpret_cast<const uint4*>(qarr + (size_t)node * HH + li * 8);
        #pragma unroll
        for (int j = 0; j < 4; ++j) q2[j] = Q.h[j];
    }
    int p0 = start + lane;
    int el = (p0 < end) ? esrc[p0] : 0;   // first 64 source indices in registers

    __half2 acc2[4];
    #pragma unroll
    for (int j = 0; j < 4; ++j) acc2[j] = __float2half2_rn(0.f);
    float s = 0.f;
    for (int c = 0; c < deg; c += 16) {
        int idx0 = c + g, idx1 = c + 8 + g;
        bool v0 = idx0 < deg, v1 = idx1 < deg;
        int sv0, sv1;
        if (c + 16 <= 64) {
            sv0 = __shfl(el, idx0);
            sv1 = __shfl(el, idx1);
        } else {
            sv0 = v0 ? esrc[start + idx0] : 0;
            sv1 = v1 ? esrc[start + idx1] : 0;
        }
        const __half* b0 = kv + (size_t)sv0 * 128 + li * 16;
        const __half* b1 = kv + (size_t)sv1 * 128 + li * 16;
        union { uint4 u; __half2 h[4]; } K0, V0, K1, V1;
        K0.u = *reinterpret_cast<const uint4*>(b0);
        V0.u = *reinterpret_cast<const uint4*>(b0 + 8);
        K1.u = *reinterpret_cast<const uint4*>(b1);
        V1.u = *reinterpret_cast<const uint4*>(b1 + 8);
        __half2 d20 = __float2half2_rn(0.f);
        __half2 d21 = __float2half2_rn(0.f);
        #pragma unroll
        for (int j = 0; j < 4; ++j) {
            d20 = __hfma2(q2[j], K0.h[j], d20);
            d21 = __hfma2(q2[j], K1.h[j], d21);
        }
        float d0 = __low2float(d20) + __high2float(d20);
        float d1 = __low2float(d21) + __high2float(d21);
        d0 += __shfl_xor(d0, 1); d1 += __shfl_xor(d1, 1);
        d0 += __shfl_xor(d0, 2); d1 += __shfl_xor(d1, 2);
        d0 += __shfl_xor(d0, 4); d1 += __shfl_xor(d1, 4);
        float e0 = v0 ? __expf(fmaxf(d0 * 0.125f, 0.f)) : 0.f;
        float e1 = v1 ? __expf(fmaxf(d1 * 0.125f, 0.f)) : 0.f;
        s += e0 + e1;
        if (v0 && li == 0) ecsr[start + idx0] = e0;
        if (v1 && li == 0) ecsr[start + idx1] = e1;
        __half2 e20 = __float2half2_rn(e0);
        __half2 e21 = __float2half2_rn(e1);
        #pragma unroll
        for (int j = 0; j < 4; ++j) {
            acc2[j] = __hfma2(e20, V0.h[j], acc2[j]);
            acc2[j] = __hfma2(e21, V1.h[j], acc2[j]);
        }
    }
    // combine the 8 groups
    #pragma unroll
    for (int off = 8; off < 64; off <<= 1) {
        s += __shfl_xor(s, off);
        #pragma unroll
        for (int j = 0; j < 4; ++j)
            acc2[j] = __hadd2(acc2[j], shfl_xor_h2(acc2[j], off));
    }
    float inv = 1.0f / (s + 1e-16f);
    float af[8];
    #pragma unroll
    for (int j = 0; j < 4; ++j) {
        af[2 * j]     = __low2float(acc2[j]);
        af[2 * j + 1] = __high2float(acc2[j]);
    }

    if (!LAST) {
        if (g == 0) {
            float4 o0, o1;
            o0.x = af[0] * inv; o0.y = af[1] * inv; o0.z = af[2] * inv; o0.w = af[3] * inv;
            o1.x = af[4] * inv; o1.y = af[5] * inv; o1.z = af[6] * inv; o1.w = af[7] * inv;
            *reinterpret_cast<float4*>(hout + (size_t)node * HH + li * 8)     = o0;
            *reinterpret_cast<float4*>(hout + (size_t)node * HH + li * 8 + 4) = o1;
        }
    } else {
        float4 w0 = *reinterpret_cast<const float4*>(Wsig + li * 8);
        float4 w1 = *reinterpret_cast<const float4*>(Wsig + li * 8 + 4);
        float t = af[0] * w0.x + af[1] * w0.y + af[2] * w0.z + af[3] * w0.w
                + af[4] * w1.x + af[5] * w1.y + af[6] * w1.z + af[7] * w1.w;
        t *= inv;
        t += __shfl_xor(t, 1);
        t += __shfl_xor(t, 2);
        t += __shfl_xor(t, 4);
        if (lane == 0) signals[node] = t + bsig[0];
    }
    // normalize in place (coalesced)
    for (int p = p0; p < end; p += 64)
        ecsr[p] *= inv;
}

extern "C" void kernel_launch(void* const* d_in, const int* in_sizes, int n_in,
                              void* d_out, int out_size, void* d_ws, size_t ws_size,
                              hipStream_t stream) {
    const float* x   = (const float*)d_in[0];
    const int*   ei  = (const int*)  d_in[1];
    const float* Wp  = (const float*)d_in[2];
    const float* bp  = (const float*)d_in[3];
    const float* Wq1 = (const float*)d_in[4];
    const float* Wk1 = (const float*)d_in[5];
    const float* Wv1 = (const float*)d_in[6];
    const float* Wq2 = (const float*)d_in[7];
    const float* Wk2 = (const float*)d_in[8];
    const float* Wv2 = (const float*)d_in[9];
    const float* Wsg = (const float*)d_in[10];
    const float* bsg = (const float*)d_in[11];

    const int N = in_sizes[0] / FF;
    const int E = in_sizes[1] / 2;
    const int* src = ei;
    const int* dst = ei + E;

    char* ws = (char*)d_ws;
    size_t off = 0;
    auto alloc = [&](size_t bytes) -> void* {
        void* p = ws + off;
        off += (bytes + 255) & ~(size_t)255;
        return p;
    };
    __half* qh   = (__half*)alloc((size_t)N * HH * 2);
    __half* kv   = (__half*)alloc((size_t)N * 128 * 2);
    float* h     = (float*)alloc((size_t)N * HH * 4);
    float* ecsr  = (float*)alloc((size_t)E * 4);
    int* inv     = (int*)alloc((size_t)E * 4);
    int* esrc    = (int*)alloc((size_t)E * 4);
    int* rank    = (int*)alloc((size_t)E * 4);
    int* deg     = (int*)alloc((size_t)N * 4);
    int* rowptr  = (int*)alloc((size_t)(N + 1) * 4);
    int* bsums   = (int*)alloc(256 * 4);
    int* boffs   = (int*)alloc(256 * 4);
    short* wf    = (short*)alloc((size_t)81920 * 2);   // W fragment tables

    float* out     = (float*)d_out;
    float* signals = out;
    float* attn1   = out + N;
    float* attn2   = out + N + E;

    // W fragment prep (independent of CSR)
    k_wprep<<<64, 256, 0, stream>>>(Wp, Wq1, Wk1, Wv1, Wq2, Wk2, Wv2, wf);

    // CSR build
    hipMemsetAsync(deg, 0, (size_t)N * 4, stream);
    int e4Blocks = ((E + 3) / 4 + 255) / 256;
    k_degree<<<e4Blocks, 256, 0, stream>>>(dst, deg, rank, E);
    int nb = (N + 1023) / 1024;
    k_scan1<<<nb, 256, 0, stream>>>(deg, rowptr, bsums, N);
    k_scan2<<<1, 256, 0, stream>>>(bsums, boffs, nb);
    k_scan3<<<(N + 1 + 255) / 256, 256, 0, stream>>>(rowptr, boffs, N, E);
    k_fill<<<e4Blocks, 256, 0, stream>>>(src, dst, rowptr, rank, esrc, inv, E);

    // GEMM grids: 64 rows/block (4 waves x 16 rows)
    int gemmBlocks = (N + 63) / 64;

    // layer 0: projection (raw, gelu applied in k_qkv)
    k_proj<<<gemmBlocks, 256, 0, stream>>>(x, wf, bp, h, N);

    const short* wfbase = wf + 32768;
    // layer 1
    k_qkv<<<gemmBlocks, 256, 0, stream>>>(h, wfbase, wfbase + 8192, wfbase + 16384,
            qh, kv, N);
    k_edge<false><<<(N + 3) / 4, 256, 0, stream>>>(qh, kv, rowptr, esrc,
            ecsr, h, nullptr, nullptr, nullptr, N);
    k_attn<<<e4Blocks, 256, 0, stream>>>(ecsr, inv, attn1, E);

    // layer 2 (+ fused signal head)
    k_qkv<<<gemmBlocks, 256, 0, stream>>>(h, wfbase + 24576, wfbase + 32768, wfbase + 40960,
            qh, kv, N);
    k_edge<true><<<(N + 3) / 4, 256, 0, stream>>>(qh, kv, rowptr, esrc,
            ecsr, nullptr, signals, Wsg, bsg, N);
    k_attn<<<e4Blocks, 256, 0, stream>>>(ecsr, inv, attn2, E);
}

// Round 9
// 304.193 us; speedup vs baseline: 1.5621x; 1.1226x over previous
//
#include <hip/hip_runtime.h>
#include <hip/hip_fp16.h>
#include <math.h>

#define FF 256
#define HH 64

typedef __attribute__((ext_vector_type(8))) short short8;
typedef __attribute__((ext_vector_type(4))) float f32x4;

// cheap gelu: A&S 7.1.26 erf approximation, |err| <= 1.5e-7
__device__ __forceinline__ float gelu_f(float x) {
    float ax = fabsf(x) * 0.70710678118654752f;
    float t = __builtin_amdgcn_rcpf(fmaf(0.3275911f, ax, 1.0f));
    float poly = t * fmaf(t, fmaf(t, fmaf(t, fmaf(t, 1.061405429f, -1.453152027f),
                  1.421413741f), -0.284496736f), 0.254829592f);
    float er = 1.0f - poly * __expf(-ax * ax);
    er = (x < 0.f) ? -er : er;
    return 0.5f * x * (1.0f + er);
}

__device__ __forceinline__ unsigned short bf16rne(float f) {
    unsigned u = __float_as_uint(f);
    unsigned r = u + 0x7FFFu + ((u >> 16) & 1u);
    return (unsigned short)(r >> 16);
}

// split f into bf16 hi + bf16 lo (RNE)
__device__ __forceinline__ void bf16split(float f, short& hi, short& lo) {
    unsigned u = __float_as_uint(f);
    unsigned r = u + 0x7FFFu + ((u >> 16) & 1u);
    hi = (short)(r >> 16);
    float fh = __uint_as_float(r & 0xFFFF0000u);
    float fl = f - fh;
    unsigned u2 = __float_as_uint(fl);
    unsigned r2 = u2 + 0x7FFFu + ((u2 >> 16) & 1u);
    lo = (short)(r2 >> 16);
}

__device__ __forceinline__ __half2 shfl_xor_h2(__half2 v, int off) {
    union { __half2 h; int i; } u;
    u.h = v;
    u.i = __shfl_xor(u.i, off, 64);
    return u.h;
}

// ---- W fragment tables in workspace (bf16 hi/lo, fragment-ordered) ----
__global__ __launch_bounds__(256) void k_wprep(
        const float* __restrict__ Wp,
        const float* __restrict__ Wq1, const float* __restrict__ Wk1, const float* __restrict__ Wv1,
        const float* __restrict__ Wq2, const float* __restrict__ Wk2, const float* __restrict__ Wv2,
        short* __restrict__ wf) {
    int total = 16384 + 6 * 4096;
    for (int gid = blockIdx.x * 256 + threadIdx.x; gid < total; gid += gridDim.x * 256) {
        const float* W;
        int fid, hibase, lobase;
        if (gid < 16384) {
            W = Wp; fid = gid; hibase = 0; lobase = 16384;
        } else {
            int t = gid - 16384;
            int m = t >> 12;
            fid = t & 4095;
            switch (m) {
                case 0: W = Wq1; break;
                case 1: W = Wk1; break;
                case 2: W = Wv1; break;
                case 3: W = Wq2; break;
                case 4: W = Wk2; break;
                default: W = Wv2; break;
            }
            hibase = 32768 + m * 8192;
            lobase = hibase + 4096;
        }
        int j    = fid & 7;
        int lane = (fid >> 3) & 63;
        int ct   = (fid >> 9) & 3;
        int s    = fid >> 11;
        int k    = s * 32 + (lane >> 4) * 8 + j;
        int col  = ct * 16 + (lane & 15);
        short hi, lo;
        bf16split(W[k * HH + col], hi, lo);
        wf[hibase + fid] = hi;
        wf[lobase + fid] = lo;
    }
}

// ---------------- device bodies for fused kernels ----------------
__device__ __forceinline__ void do_degree(int bid, const int* __restrict__ dst,
        int* __restrict__ deg, int* __restrict__ rank, int E) {
    int e0 = (bid * 256 + threadIdx.x) * 4;
    if (e0 + 3 < E) {
        int4 d4 = *reinterpret_cast<const int4*>(dst + e0);
        int4 r4;
        r4.x = atomicAdd(&deg[d4.x], 1);
        r4.y = atomicAdd(&deg[d4.y], 1);
        r4.z = atomicAdd(&deg[d4.z], 1);
        r4.w = atomicAdd(&deg[d4.w], 1);
        *reinterpret_cast<int4*>(rank + e0) = r4;
    } else {
        for (int e = e0; e < E; ++e) rank[e] = atomicAdd(&deg[dst[e]], 1);
    }
}

__device__ __forceinline__ void do_fill(int bid, const int* __restrict__ src,
        const int* __restrict__ dst, const int* __restrict__ rowptr,
        const int* __restrict__ rank,
        int* __restrict__ esrc, int* __restrict__ inv, int E) {
    int e0 = (bid * 256 + threadIdx.x) * 4;
    if (e0 + 3 < E) {
        int4 d4 = *reinterpret_cast<const int4*>(dst + e0);
        int4 s4 = *reinterpret_cast<const int4*>(src + e0);
        int4 r4 = *reinterpret_cast<const int4*>(rank + e0);
        int p0 = rowptr[d4.x] + r4.x;
        int p1 = rowptr[d4.y] + r4.y;
        int p2 = rowptr[d4.z] + r4.z;
        int p3 = rowptr[d4.w] + r4.w;
        esrc[p0] = s4.x;
        esrc[p1] = s4.y;
        esrc[p2] = s4.z;
        esrc[p3] = s4.w;
        *reinterpret_cast<int4*>(inv + e0) = (int4){p0, p1, p2, p3};
    } else {
        for (int e = e0; e < E; ++e) {
            int pos = rowptr[dst[e]] + rank[e];
            esrc[pos] = src[e];
            inv[e] = pos;
        }
    }
}

__device__ __forceinline__ void do_attn(int bid, const float* __restrict__ ecsr,
        const int* __restrict__ inv, float* __restrict__ attn, int E) {
    int e0 = (bid * 256 + threadIdx.x) * 4;
    if (e0 + 3 < E) {
        int4 i4 = *reinterpret_cast<const int4*>(inv + e0);
        float4 a;
        a.x = ecsr[i4.x]; a.y = ecsr[i4.y]; a.z = ecsr[i4.z]; a.w = ecsr[i4.w];
        *reinterpret_cast<float4*>(attn + e0) = a;
    } else {
        for (int e = e0; e < E; ++e) attn[e] = ecsr[inv[e]];
    }
}

__device__ __forceinline__ void do_proj(int bid, const float* __restrict__ x,
        const short* __restrict__ wf, const float* __restrict__ b,
        float* __restrict__ h, int n) {
    if (bid * 64 >= n) return;
    int lane = threadIdx.x & 63;
    int w    = threadIdx.x >> 6;
    int m    = lane & 15, g = lane >> 4;
    int rowc = min(bid * 64 + w * 16 + m, n - 1);
    const float* xrow = x + (size_t)rowc * FF + g * 8;
    const short* wlo = wf + 16384;
    f32x4 acc[4];
    #pragma unroll
    for (int ct = 0; ct < 4; ++ct) acc[ct] = (f32x4){0.f, 0.f, 0.f, 0.f};
    #pragma unroll
    for (int s = 0; s < 8; ++s) {
        float4 a0 = *reinterpret_cast<const float4*>(xrow + s * 32);
        float4 a1 = *reinterpret_cast<const float4*>(xrow + s * 32 + 4);
        float av[8] = {a0.x, a0.y, a0.z, a0.w, a1.x, a1.y, a1.z, a1.w};
        short8 ah, al;
        #pragma unroll
        for (int j = 0; j < 8; ++j) { short hi, lo; bf16split(av[j], hi, lo); ah[j] = hi; al[j] = lo; }
        #pragma unroll
        for (int ct = 0; ct < 4; ++ct) {
            int fo = ((s * 4 + ct) * 64 + lane) * 8;
            short8 bh = *reinterpret_cast<const short8*>(wf + fo);
            short8 bl = *reinterpret_cast<const short8*>(wlo + fo);
            acc[ct] = __builtin_amdgcn_mfma_f32_16x16x32_bf16(ah, bh, acc[ct], 0, 0, 0);
            acc[ct] = __builtin_amdgcn_mfma_f32_16x16x32_bf16(al, bh, acc[ct], 0, 0, 0);
            acc[ct] = __builtin_amdgcn_mfma_f32_16x16x32_bf16(ah, bl, acc[ct], 0, 0, 0);
        }
    }
    int orow0 = bid * 64 + w * 16 + g * 4;
    #pragma unroll
    for (int ct = 0; ct < 4; ++ct) {
        int col = ct * 16 + m;
        float bias = b[col];
        #pragma unroll
        for (int r = 0; r < 4; ++r) {
            int row = orow0 + r;
            if (row < n) h[(size_t)row * HH + col] = acc[ct][r] + bias;   // raw; gelu in qkv
        }
    }
}

// kv row layout (128 halves): block b=c>>3 : k[c] at b*16+(c&7), v[c] at b*16+8+(c&7)
__device__ __forceinline__ void do_qkv(int bid, const float* __restrict__ hsrc,
        const short* __restrict__ wfq, const short* __restrict__ wfk, const short* __restrict__ wfv,
        __half* __restrict__ qh, __half* __restrict__ kv, int n) {
    if (bid * 64 >= n) return;
    int lane = threadIdx.x & 63;
    int w    = threadIdx.x >> 6;
    int m    = lane & 15, g = lane >> 4;
    int rowc = min(bid * 64 + w * 16 + m, n - 1);
    const float* hrow = hsrc + (size_t)rowc * HH + g * 8;
    f32x4 aq[4], ak[4], av_[4];
    #pragma unroll
    for (int ct = 0; ct < 4; ++ct) {
        aq[ct] = (f32x4){0.f, 0.f, 0.f, 0.f};
        ak[ct] = (f32x4){0.f, 0.f, 0.f, 0.f};
        av_[ct] = (f32x4){0.f, 0.f, 0.f, 0.f};
    }
    #pragma unroll
    for (int s = 0; s < 2; ++s) {
        float4 a0 = *reinterpret_cast<const float4*>(hrow + s * 32);
        float4 a1 = *reinterpret_cast<const float4*>(hrow + s * 32 + 4);
        float avv[8] = {a0.x, a0.y, a0.z, a0.w, a1.x, a1.y, a1.z, a1.w};
        short8 ah;
        #pragma unroll
        for (int j = 0; j < 8; ++j) ah[j] = (short)bf16rne(gelu_f(avv[j]));
        #pragma unroll
        for (int ct = 0; ct < 4; ++ct) {
            int fo = ((s * 4 + ct) * 64 + lane) * 8;
            short8 qh8 = *reinterpret_cast<const short8*>(wfq + fo);
            short8 ql8 = *reinterpret_cast<const short8*>(wfq + 4096 + fo);
            short8 kh8 = *reinterpret_cast<const short8*>(wfk + fo);
            short8 kl8 = *reinterpret_cast<const short8*>(wfk + 4096 + fo);
            short8 vh8 = *reinterpret_cast<const short8*>(wfv + fo);
            short8 vl8 = *reinterpret_cast<const short8*>(wfv + 4096 + fo);
            aq[ct] = __builtin_amdgcn_mfma_f32_16x16x32_bf16(ah, qh8, aq[ct], 0, 0, 0);
            aq[ct] = __builtin_amdgcn_mfma_f32_16x16x32_bf16(ah, ql8, aq[ct], 0, 0, 0);
            ak[ct] = __builtin_amdgcn_mfma_f32_16x16x32_bf16(ah, kh8, ak[ct], 0, 0, 0);
            ak[ct] = __builtin_amdgcn_mfma_f32_16x16x32_bf16(ah, kl8, ak[ct], 0, 0, 0);
            av_[ct] = __builtin_amdgcn_mfma_f32_16x16x32_bf16(ah, vh8, av_[ct], 0, 0, 0);
            av_[ct] = __builtin_amdgcn_mfma_f32_16x16x32_bf16(ah, vl8, av_[ct], 0, 0, 0);
        }
    }
    int orow0 = bid * 64 + w * 16 + g * 4;
    #pragma unroll
    for (int ct = 0; ct < 4; ++ct) {
        int col = ct * 16 + m;
        int cb  = (col >> 3) * 16 + (col & 7);
        #pragma unroll
        for (int r = 0; r < 4; ++r) {
            int row = orow0 + r;
            if (row < n) {
                qh[(size_t)row * HH + col]     = __float2half(aq[ct][r]);
                kv[(size_t)row * 128 + cb]     = __float2half(ak[ct][r]);
                kv[(size_t)row * 128 + cb + 8] = __float2half(av_[ct][r]);
            }
        }
    }
}

// ---------------- fused dispatches (parity-interleaved block split) ----------------
__global__ __launch_bounds__(256) void k_proj_degree(
        const float* __restrict__ x, const short* __restrict__ wf,
        const float* __restrict__ b, float* __restrict__ h, int n,
        const int* __restrict__ dst, int* __restrict__ deg, int* __restrict__ rank, int E) {
    int bid = blockIdx.x >> 1;
    if ((blockIdx.x & 1) == 0) do_proj(bid, x, wf, b, h, n);
    else                       do_degree(bid, dst, deg, rank, E);
}

__global__ __launch_bounds__(256) void k_qkv_fill(
        const float* __restrict__ hsrc,
        const short* __restrict__ wfq, const short* __restrict__ wfk, const short* __restrict__ wfv,
        __half* __restrict__ qh, __half* __restrict__ kv, int n,
        const int* __restrict__ src, const int* __restrict__ dst,
        const int* __restrict__ rowptr, const int* __restrict__ rank,
        int* __restrict__ esrc, int* __restrict__ inv, int E) {
    int bid = blockIdx.x >> 1;
    if ((blockIdx.x & 1) == 0) do_qkv(bid, hsrc, wfq, wfk, wfv, qh, kv, n);
    else                       do_fill(bid, src, dst, rowptr, rank, esrc, inv, E);
}

__global__ __launch_bounds__(256) void k_qkv_attn(
        const float* __restrict__ hsrc,
        const short* __restrict__ wfq, const short* __restrict__ wfk, const short* __restrict__ wfv,
        __half* __restrict__ qh, __half* __restrict__ kv, int n,
        const float* __restrict__ ecsr, const int* __restrict__ inv,
        float* __restrict__ attn, int E) {
    int bid = blockIdx.x >> 1;
    if ((blockIdx.x & 1) == 0) do_qkv(bid, hsrc, wfq, wfk, wfv, qh, kv, n);
    else                       do_attn(bid, ecsr, inv, attn, E);
}

__global__ __launch_bounds__(256) void k_attn(const float* __restrict__ ecsr,
        const int* __restrict__ inv, float* __restrict__ attn, int E) {
    do_attn(blockIdx.x, ecsr, inv, attn, E);
}

// ---------------- scans ----------------
__global__ __launch_bounds__(256) void k_scan1(const int* __restrict__ deg,
        int* __restrict__ out, int* __restrict__ bsums, int n) {
    __shared__ int lds[256];
    int t = threadIdx.x;
    int base = blockIdx.x * 1024 + t * 4;
    int v0 = (base     < n) ? deg[base]     : 0;
    int v1 = (base + 1 < n) ? deg[base + 1] : 0;
    int v2 = (base + 2 < n) ? deg[base + 2] : 0;
    int v3 = (base + 3 < n) ? deg[base + 3] : 0;
    int s = v0 + v1 + v2 + v3;
    int val = s;
    lds[t] = val;
    __syncthreads();
    #pragma unroll
    for (int off = 1; off < 256; off <<= 1) {
        int tmp = (t >= off) ? lds[t - off] : 0;
        __syncthreads();
        val += tmp;
        lds[t] = val;
        __syncthreads();
    }
    if (t == 255) bsums[blockIdx.x] = val;
    int excl = val - s;
    if (base     < n) out[base]     = excl;
    if (base + 1 < n) out[base + 1] = excl + v0;
    if (base + 2 < n) out[base + 2] = excl + v0 + v1;
    if (base + 3 < n) out[base + 3] = excl + v0 + v1 + v2;
}

__global__ __launch_bounds__(256) void k_scan2(const int* __restrict__ bsums,
        int* __restrict__ boffs, int nb) {
    __shared__ int lds[256];
    int t = threadIdx.x;
    int s = (t < nb) ? bsums[t] : 0;
    int val = s;
    lds[t] = val;
    __syncthreads();
    #pragma unroll
    for (int off = 1; off < 256; off <<= 1) {
        int tmp = (t >= off) ? lds[t - off] : 0;
        __syncthreads();
        val += tmp;
        lds[t] = val;
        __syncthreads();
    }
    if (t < nb) boffs[t] = val - s;
}

__global__ __launch_bounds__(256) void k_scan3(int* __restrict__ rowptr,
        const int* __restrict__ boffs, int n, int E) {
    int i = blockIdx.x * 256 + threadIdx.x;
    if (i < n) rowptr[i] += boffs[i >> 10];
    if (i == n) rowptr[n] = E;
}

// ---------------- GAT edge phase: one wave/node, 8 lanes/edge, f16 packed math ----
template<bool LAST>
__global__ __launch_bounds__(256) void k_edge(
        const __half* __restrict__ qarr, const __half* __restrict__ kv,
        const int* __restrict__ rowptr,
        const int* __restrict__ esrc,
        float* __restrict__ ecsr,
        float* __restrict__ hout,
        float* __restrict__ signals,
        const float* __restrict__ Wsig, const float* __restrict__ bsig,
        int n) {
    int node = blockIdx.x * 4 + (threadIdx.x >> 6);
    if (node >= n) return;
    int lane = threadIdx.x & 63;
    int li = lane & 7, g = lane >> 3;
    int start = rowptr[node], end = rowptr[node + 1];
    int deg = end - start;
    __half2 q2[4];
    {
        union { uint4 u; __half2 h[4]; } Q;
        Q.u = *reinterpret_cast<const uint4*>(qarr + (size_t)node * HH + li * 8);
        #pragma unroll
        for (int j = 0; j < 4; ++j) q2[j] = Q.h[j];
    }
    int p0 = start + lane;
    int el = (p0 < end) ? esrc[p0] : 0;   // first 64 source indices in registers

    __half2 acc2[4];
    #pragma unroll
    for (int j = 0; j < 4; ++j) acc2[j] = __float2half2_rn(0.f);
    float s = 0.f;
    for (int c = 0; c < deg; c += 16) {
        int idx0 = c + g, idx1 = c + 8 + g;
        bool v0 = idx0 < deg, v1 = idx1 < deg;
        int sv0, sv1;
        if (c + 16 <= 64) {
            sv0 = __shfl(el, idx0);
            sv1 = __shfl(el, idx1);
        } else {
            sv0 = v0 ? esrc[start + idx0] : 0;
            sv1 = v1 ? esrc[start + idx1] : 0;
        }
        const __half* b0 = kv + (size_t)sv0 * 128 + li * 16;
        const __half* b1 = kv + (size_t)sv1 * 128 + li * 16;
        union { uint4 u; __half2 h[4]; } K0, V0, K1, V1;
        K0.u = *reinterpret_cast<const uint4*>(b0);
        V0.u = *reinterpret_cast<const uint4*>(b0 + 8);
        K1.u = *reinterpret_cast<const uint4*>(b1);
        V1.u = *reinterpret_cast<const uint4*>(b1 + 8);
        __half2 d20 = __float2half2_rn(0.f);
        __half2 d21 = __float2half2_rn(0.f);
        #pragma unroll
        for (int j = 0; j < 4; ++j) {
            d20 = __hfma2(q2[j], K0.h[j], d20);
            d21 = __hfma2(q2[j], K1.h[j], d21);
        }
        float d0 = __low2float(d20) + __high2float(d20);
        float d1 = __low2float(d21) + __high2float(d21);
        d0 += __shfl_xor(d0, 1); d1 += __shfl_xor(d1, 1);
        d0 += __shfl_xor(d0, 2); d1 += __shfl_xor(d1, 2);
        d0 += __shfl_xor(d0, 4); d1 += __shfl_xor(d1, 4);
        float e0 = v0 ? __expf(fmaxf(d0 * 0.125f, 0.f)) : 0.f;
        float e1 = v1 ? __expf(fmaxf(d1 * 0.125f, 0.f)) : 0.f;
        s += e0 + e1;
        if (v0 && li == 0) ecsr[start + idx0] = e0;
        if (v1 && li == 0) ecsr[start + idx1] = e1;
        __half2 e20 = __float2half2_rn(e0);
        __half2 e21 = __float2half2_rn(e1);
        #pragma unroll
        for (int j = 0; j < 4; ++j) {
            acc2[j] = __hfma2(e20, V0.h[j], acc2[j]);
            acc2[j] = __hfma2(e21, V1.h[j], acc2[j]);
        }
    }
    // combine the 8 groups
    #pragma unroll
    for (int off = 8; off < 64; off <<= 1) {
        s += __shfl_xor(s, off);
        #pragma unroll
        for (int j = 0; j < 4; ++j)
            acc2[j] = __hadd2(acc2[j], shfl_xor_h2(acc2[j], off));
    }
    float inv = 1.0f / (s + 1e-16f);
    float af[8];
    #pragma unroll
    for (int j = 0; j < 4; ++j) {
        af[2 * j]     = __low2float(acc2[j]);
        af[2 * j + 1] = __high2float(acc2[j]);
    }

    if (!LAST) {
        if (g == 0) {
            float4 o0, o1;
            o0.x = af[0] * inv; o0.y = af[1] * inv; o0.z = af[2] * inv; o0.w = af[3] * inv;
            o1.x = af[4] * inv; o1.y = af[5] * inv; o1.z = af[6] * inv; o1.w = af[7] * inv;
            *reinterpret_cast<float4*>(hout + (size_t)node * HH + li * 8)     = o0;
            *reinterpret_cast<float4*>(hout + (size_t)node * HH + li * 8 + 4) = o1;
        }
    } else {
        float4 w0 = *reinterpret_cast<const float4*>(Wsig + li * 8);
        float4 w1 = *reinterpret_cast<const float4*>(Wsig + li * 8 + 4);
        float t = af[0] * w0.x + af[1] * w0.y + af[2] * w0.z + af[3] * w0.w
                + af[4] * w1.x + af[5] * w1.y + af[6] * w1.z + af[7] * w1.w;
        t *= inv;
        t += __shfl_xor(t, 1);
        t += __shfl_xor(t, 2);
        t += __shfl_xor(t, 4);
        if (lane == 0) signals[node] = t + bsig[0];
    }
    // normalize in place (coalesced)
    for (int p = p0; p < end; p += 64)
        ecsr[p] *= inv;
}

extern "C" void kernel_launch(void* const* d_in, const int* in_sizes, int n_in,
                              void* d_out, int out_size, void* d_ws, size_t ws_size,
                              hipStream_t stream) {
    const float* x   = (const float*)d_in[0];
    const int*   ei  = (const int*)  d_in[1];
    const float* Wp  = (const float*)d_in[2];
    const float* bp  = (const float*)d_in[3];
    const float* Wq1 = (const float*)d_in[4];
    const float* Wk1 = (const float*)d_in[5];
    const float* Wv1 = (const float*)d_in[6];
    const float* Wq2 = (const float*)d_in[7];
    const float* Wk2 = (const float*)d_in[8];
    const float* Wv2 = (const float*)d_in[9];
    const float* Wsg = (const float*)d_in[10];
    const float* bsg = (const float*)d_in[11];

    const int N = in_sizes[0] / FF;
    const int E = in_sizes[1] / 2;
    const int* src = ei;
    const int* dst = ei + E;

    char* ws = (char*)d_ws;
    size_t off = 0;
    auto alloc = [&](size_t bytes) -> void* {
        void* p = ws + off;
        off += (bytes + 255) & ~(size_t)255;
        return p;
    };
    __half* qh   = (__half*)alloc((size_t)N * HH * 2);
    __half* kv   = (__half*)alloc((size_t)N * 128 * 2);
    float* h     = (float*)alloc((size_t)N * HH * 4);
    float* ecsr  = (float*)alloc((size_t)E * 4);
    int* inv     = (int*)alloc((size_t)E * 4);
    int* esrc    = (int*)alloc((size_t)E * 4);
    int* rank    = (int*)alloc((size_t)E * 4);
    int* deg     = (int*)alloc((size_t)N * 4);
    int* rowptr  = (int*)alloc((size_t)(N + 1) * 4);
    int* bsums   = (int*)alloc(256 * 4);
    int* boffs   = (int*)alloc(256 * 4);
    short* wf    = (short*)alloc((size_t)81920 * 2);   // W fragment tables

    float* out     = (float*)d_out;
    float* signals = out;
    float* attn1   = out + N;
    float* attn2   = out + N + E;

    // W fragment prep + deg zero (both independent of everything else)
    k_wprep<<<64, 256, 0, stream>>>(Wp, Wq1, Wk1, Wv1, Wq2, Wk2, Wv2, wf);
    hipMemsetAsync(deg, 0, (size_t)N * 4, stream);

    int gemmBlocks = (N + 63) / 64;            // 64 rows/block (4 waves x 16 rows)
    int e4Blocks   = ((E + 3) / 4 + 255) / 256; // 1024 edges/block
    int fused1     = 2 * max(gemmBlocks, e4Blocks);

    // proj (MFMA, compute) ∥ degree+rank (device atomics, latency)
    k_proj_degree<<<fused1, 256, 0, stream>>>(x, wf, bp, h, N, dst, deg, rank, E);

    int nb = (N + 1023) / 1024;
    k_scan1<<<nb, 256, 0, stream>>>(deg, rowptr, bsums, N);
    k_scan2<<<1, 256, 0, stream>>>(bsums, boffs, nb);
    k_scan3<<<(N + 1 + 255) / 256, 256, 0, stream>>>(rowptr, boffs, N, E);

    const short* wfbase = wf + 32768;
    // qkv1 (compute) ∥ fill (scatter latency)
    k_qkv_fill<<<fused1, 256, 0, stream>>>(h, wfbase, wfbase + 8192, wfbase + 16384,
            qh, kv, N, src, dst, rowptr, rank, esrc, inv, E);
    k_edge<false><<<(N + 3) / 4, 256, 0, stream>>>(qh, kv, rowptr, esrc,
            ecsr, h, nullptr, nullptr, nullptr, N);

    // qkv2 (compute) ∥ attn1 (gather)
    k_qkv_attn<<<fused1, 256, 0, stream>>>(h, wfbase + 24576, wfbase + 32768, wfbase + 40960,
            qh, kv, N, ecsr, inv, attn1, E);
    k_edge<true><<<(N + 3) / 4, 256, 0, stream>>>(qh, kv, rowptr, esrc,
            ecsr, nullptr, signals, Wsg, bsg, N);
    k_attn<<<e4Blocks, 256, 0, stream>>>(ecsr, inv, attn2, E);
}